// Round 11
// baseline (125.445 us; speedup 1.0000x reference)
//
#include <hip/hip_runtime.h>
#include <math.h>

// Problem constants
#define NB    64
#define L0    128
#define C0    16
#define KW    5
#define NF    8
#define CH1   128
#define CH2   1024
#define CH3   8192
#define NCHUNK 8
#define NS     4
#define SLICE  29
#define TROWS  (SLICE + 4)    // 33
#define Y1R    (SLICE + 8)    // 37
#define STR    (SLICE + 12)   // 41
#define NFH    4
#define NBATCH 4              // batches per block (2 blocks/CU)
#define NBG    (NB / NBATCH)  // 16
#define NBLOCKS (NCHUNK * NBG * NS)   // 512

typedef float v4f __attribute__((ext_vector_type(4)));

__device__ __forceinline__ v4f splat(float s) { return (v4f){s, s, s, s}; }
// a*s + c elementwise -> v_pk_fma_f32 pairs on gfx950
__device__ __forceinline__ v4f vfma(v4f a, float s, v4f c) {
    return __builtin_elementwise_fma(a, splat(s), c);
}
__device__ __forceinline__ v4f vrelu(v4f a) {
    return __builtin_elementwise_max(a, splat(0.f));
}

// ---------------------------------------------------------------------------
// R11 = R9 (best: unroll-2 ring-2 W prefetch, NBATCH=4 packed fp32,
// 2 blocks/CU) + two orthogonal cuts:
//  (a) cold k3/b3 + initial W ring loads hoisted BEFORE the conv1/conv2
//      preamble (no LDS dependency -> their miss latency overlaps staging);
//  (b) finish fused via last-block ticket (device-scope atomicAdd + fences;
//      agent-scope atomic loads of partials respect XCD-L2 non-coherence),
//      killing the separate finish launch. Counter zeroed per call via a
//      4-byte hipMemsetAsync (graph-capture-safe, same work every call).
// ---------------------------------------------------------------------------
__global__ __launch_bounds__(256, 2) void actor_fused_kernel(
    const float* __restrict__ state,   // [64][128][16]
    const float* __restrict__ k1,      // [5][1][128]
    const float* __restrict__ b1,      // [128]
    const float* __restrict__ k2,      // [5][1][1024]
    const float* __restrict__ b2,      // [1024]
    const float* __restrict__ k3,      // [5][1][8192]
    const float* __restrict__ b3,      // [8192]
    const float* __restrict__ W,       // [950272][2]
    const float* __restrict__ bd,      // [2]
    float* __restrict__ partials,      // [64][8][4][2]
    unsigned int* __restrict__ counter,// [1], zeroed per call
    float* __restrict__ out)           // [64][2]
{
    const int chunk = blockIdx.x;      // 0..7
    const int bg    = blockIdx.y;      // 0..15
    const int slice = blockIdx.z;      // 0..3
    const int t0    = slice * SLICE;
    const int tid   = threadIdx.x;     // 0..255
    const int c3loc = tid >> 1;        // 0..127
    const int fh    = tid & 1;         // 0..1
    const int c3    = chunk * 128 + c3loc;

    __shared__ float s_state[NBATCH][STR][2];   // 1.3 KB
    __shared__ v4f   s_y1[Y1R][16];             // lanes = batches, 9.25 KB
    __shared__ v4f   tile[TROWS][128];          // lanes = batches, 66 KB

    // ---- EARLY cold loads: no LDS dependency; latency overlaps staging ----
    const v4f* __restrict__ wb =
        (const v4f*)W + (size_t)t0 * 4096 + (size_t)c3 * 4 + fh * 2;
    v4f qa0 = wb[0],    qa1 = wb[1];       // W[t]   (even ring slot)
    v4f qb0 = wb[4096], qb1 = wb[4097];    // W[t+1] (odd ring slot)

    float kw[KW][NFH], bv[NFH];
#pragma unroll
    for (int k = 0; k < KW; ++k)
#pragma unroll
        for (int f = 0; f < NFH; ++f)
            kw[k][f] = k3[k * CH3 + c3 * NF + fh * NFH + f];
#pragma unroll
    for (int f = 0; f < NFH; ++f)
        bv[f] = b3[c3 * NF + fh * NFH + f];

    // ---- stage state: wave bb = tid>>6 owns batch bg*4+bb ----
    {
        int bb = tid >> 6, lt = tid & 63;
        const float* sp = state + (size_t)(bg * NBATCH + bb) * L0 * C0
                        + (size_t)t0 * C0 + chunk * 2;
        for (int i = lt; i < STR * 2; i += 64) {
            int r = i >> 1, c = i & 1;
            s_state[bb][r][c] = sp[r * C0 + c];
        }
    }
    __syncthreads();

    // ---- conv1: wave bb writes component bb of s_y1 ----
    {
        int bb = tid >> 6, lt = tid & 63;
        for (int i = lt; i < Y1R * 16; i += 64) {
            int r = i >> 4, jloc = i & 15;
            int j = chunk * 16 + jloc;
            int cloc = jloc >> 3;
            float acc = b1[j];
#pragma unroll
            for (int k = 0; k < KW; ++k)
                acc = fmaf(s_state[bb][r + k][cloc], k1[k * CH1 + j], acc);
            ((float*)&s_y1[r][jloc])[bb] = fmaxf(acc, 0.f);
        }
    }
    __syncthreads();

    // ---- conv2: col c = tid&127, row-half h = tid>>7, 4 batches packed ----
    {
        int c = tid & 127, h = tid >> 7;
        int m = chunk * 128 + c;
        int jloc = c >> 3;
        float kk[KW], b2v = b2[m];
#pragma unroll
        for (int k = 0; k < KW; ++k) kk[k] = k2[k * CH2 + m];
        int r0i = h ? 17 : 0, r1i = h ? TROWS : 17;
        v4f u0 = s_y1[r0i + 0][jloc];
        v4f u1 = s_y1[r0i + 1][jloc];
        v4f u2 = s_y1[r0i + 2][jloc];
        v4f u3 = s_y1[r0i + 3][jloc];
        for (int r = r0i; r < r1i; ++r) {
            v4f u4 = s_y1[r + 4][jloc];
            v4f acc = splat(b2v);
            acc = vfma(u0, kk[0], acc);
            acc = vfma(u1, kk[1], acc);
            acc = vfma(u2, kk[2], acc);
            acc = vfma(u3, kk[3], acc);
            acc = vfma(u4, kk[4], acc);
            tile[r][c] = vrelu(acc);
            u0 = u1; u1 = u2; u2 = u3; u3 = u4;
        }
    }

    __syncthreads();   // tile ready

    // ---- main loop: unroll-2, ring-2 W slots, double-row ds prefetch ----
    v4f accx = splat(0.f), accy = splat(0.f);

    v4f r0 = tile[0][c3loc], r1 = tile[1][c3loc], r2 = tile[2][c3loc],
        r3 = tile[3][c3loc], r4 = tile[4][c3loc], rn = tile[5][c3loc];

#define SUBITER(A0, A1, A2, A3, A4, Q0, Q1)                                   \
    {                                                                          \
        v4f v0 = splat(bv[0]), v1 = splat(bv[1]);                              \
        v4f v2 = splat(bv[2]), v3 = splat(bv[3]);                              \
        v0 = vfma(A0, kw[0][0], v0); v1 = vfma(A0, kw[0][1], v1);              \
        v2 = vfma(A0, kw[0][2], v2); v3 = vfma(A0, kw[0][3], v3);              \
        v0 = vfma(A1, kw[1][0], v0); v1 = vfma(A1, kw[1][1], v1);              \
        v2 = vfma(A1, kw[1][2], v2); v3 = vfma(A1, kw[1][3], v3);              \
        v0 = vfma(A2, kw[2][0], v0); v1 = vfma(A2, kw[2][1], v1);              \
        v2 = vfma(A2, kw[2][2], v2); v3 = vfma(A2, kw[2][3], v3);              \
        v0 = vfma(A3, kw[3][0], v0); v1 = vfma(A3, kw[3][1], v1);              \
        v2 = vfma(A3, kw[3][2], v2); v3 = vfma(A3, kw[3][3], v3);              \
        v0 = vfma(A4, kw[4][0], v0); v1 = vfma(A4, kw[4][1], v1);              \
        v2 = vfma(A4, kw[4][2], v2); v3 = vfma(A4, kw[4][3], v3);              \
        v0 = vrelu(v0); v1 = vrelu(v1); v2 = vrelu(v2); v3 = vrelu(v3);        \
        accx = vfma(v0, Q0.x, accx); accy = vfma(v0, Q0.y, accy);              \
        accx = vfma(v1, Q0.z, accx); accy = vfma(v1, Q0.w, accy);              \
        accx = vfma(v2, Q1.x, accx); accy = vfma(v2, Q1.y, accy);              \
        accx = vfma(v3, Q1.z, accx); accy = vfma(v3, Q1.w, accy);              \
    }

    for (int t = 0; t < SLICE - 1; t += 2) {   // t = 0,2,...,26
        // ds prefetch for the NEXT double-iter
        v4f na = tile[t + 6][c3loc];
        int tb = (t + 7 < TROWS) ? (t + 7) : (TROWS - 1);
        v4f nb = tile[tb][c3loc];

        SUBITER(r0, r1, r2, r3, r4, qa0, qa1);
        qa0 = wb[(size_t)(t + 2) * 4096];
        qa1 = wb[(size_t)(t + 2) * 4096 + 1];

        SUBITER(r1, r2, r3, r4, rn, qb0, qb1);
        int tp = (t + 3 < SLICE) ? (t + 3) : (SLICE - 1);
        qb0 = wb[(size_t)tp * 4096];
        qb1 = wb[(size_t)tp * 4096 + 1];

        r0 = r2; r1 = r3; r2 = r4; r3 = rn; r4 = na; rn = nb;
    }
    SUBITER(r0, r1, r2, r3, r4, qa0, qa1);   // tail t = 28
#undef SUBITER

    // ---- reductions: 4 batches x 2 outputs ----
    float ax[NBATCH] = {accx.x, accx.y, accx.z, accx.w};
    float ay[NBATCH] = {accy.x, accy.y, accy.z, accy.w};
#pragma unroll
    for (int bb = 0; bb < NBATCH; ++bb)
#pragma unroll
        for (int d = 32; d >= 1; d >>= 1) {
            ax[bb] += __shfl_down(ax[bb], d, 64);
            ay[bb] += __shfl_down(ay[bb], d, 64);
        }
    __shared__ float red[4][NBATCH][2];
    int wave = tid >> 6, lane = tid & 63;
    if (lane == 0) {
#pragma unroll
        for (int bb = 0; bb < NBATCH; ++bb) {
            red[wave][bb][0] = ax[bb];
            red[wave][bb][1] = ay[bb];
        }
    }
    __syncthreads();
    if (tid < NBATCH * 2) {
        int bb = tid >> 1, a = tid & 1;
        float s = (red[0][bb][a] + red[1][bb][a]) + (red[2][bb][a] + red[3][bb][a]);
        int b = bg * NBATCH + bb;
        partials[(((size_t)b * NCHUNK + chunk) * NS + slice) * 2 + a] = s;
    }

    // ---- last-block ticket: fused finish (tanh epilogue) ----
    __threadfence();                    // publish partials (device scope)
    __syncthreads();
    __shared__ unsigned int s_ticket;
    if (tid == 0) s_ticket = atomicAdd(counter, 1u);
    __syncthreads();
    if (s_ticket == NBLOCKS - 1) {
        __threadfence();                // acquire
        if (tid < NB * 2) {
            int b = tid >> 1, a = tid & 1;
            float s = bd[a];
#pragma unroll
            for (int p = 0; p < NCHUNK * NS; ++p)
                s += __hip_atomic_load(
                        &partials[((size_t)b * NCHUNK * NS + p) * 2 + a],
                        __ATOMIC_RELAXED, __HIP_MEMORY_SCOPE_AGENT);
            out[b * 2 + a] = tanhf(s);
        }
    }
}

extern "C" void kernel_launch(void* const* d_in, const int* in_sizes, int n_in,
                              void* d_out, int out_size, void* d_ws, size_t ws_size,
                              hipStream_t stream) {
    const float* state = (const float*)d_in[0];
    const float* k1    = (const float*)d_in[1];
    const float* b1    = (const float*)d_in[2];
    const float* k2    = (const float*)d_in[3];
    const float* b2    = (const float*)d_in[4];
    const float* k3    = (const float*)d_in[5];
    const float* b3    = (const float*)d_in[6];
    const float* W     = (const float*)d_in[7];
    const float* bd    = (const float*)d_in[8];
    float* out = (float*)d_out;

    float* partials = (float*)d_ws;                                // 16 KB
    unsigned int* counter = (unsigned int*)((char*)d_ws + 65536);  // 4 B

    hipMemsetAsync(counter, 0, sizeof(unsigned int), stream);

    dim3 grid(NCHUNK, NBG, NS);
    actor_fused_kernel<<<grid, 256, 0, stream>>>(
        state, k1, b1, k2, b2, k3, b3, W, bd, partials, counter, out);
}

// Round 12
// 92.455 us; speedup vs baseline: 1.3568x; 1.3568x over previous
//
#include <hip/hip_runtime.h>
#include <math.h>

// Problem constants
#define NB    64
#define L0    128
#define C0    16
#define KW    5
#define NF    8
#define CH1   128
#define CH2   1024
#define CH3   8192
#define NCHUNK 8
#define NS     4
#define SLICE  29
#define TROWS  (SLICE + 4)    // 33
#define Y1R    (SLICE + 8)    // 37
#define STR    (SLICE + 12)   // 41
#define NFH    4
#define NBATCH 4              // batches per block (2 blocks/CU)
#define NBG    (NB / NBATCH)  // 16

typedef float v4f __attribute__((ext_vector_type(4)));

__device__ __forceinline__ v4f splat(float s) { return (v4f){s, s, s, s}; }
// a*s + c elementwise -> v_pk_fma_f32 pairs on gfx950
__device__ __forceinline__ v4f vfma(v4f a, float s, v4f c) {
    return __builtin_elementwise_fma(a, splat(s), c);
}
__device__ __forceinline__ v4f vrelu(v4f a) {
    return __builtin_elementwise_max(a, splat(0.f));
}

// ---------------------------------------------------------------------------
// R12 = R9 (best measured: 89.3 us total; unroll-2 ring-2 W prefetch,
// NBATCH=4 packed fp32, 2 blocks/CU) + ONE isolated change: cold k3/b3 and
// initial W-ring loads hoisted to the top, before any LDS dependency, so
// their first-touch miss latency (W is re-restored by the harness every
// iteration -> L3/HBM-cold) overlaps the conv1/conv2 staging compute.
// R11's last-block-ticket epilogue is REVERTED: its all-block device-scope
// __threadfence() lowered to TCC-wide L2 writeback/invalidate ops that
// serialized and evicted W for co-resident blocks (fused 14.7 -> 58.9 us,
// FETCH unchanged => L3 refills, pure latency). Separate finish kernel.
// blockIdx.x = chunk pins each 950 KB W-slice to one XCD's L2 (linear%8).
// ---------------------------------------------------------------------------
__global__ __launch_bounds__(256, 2) void actor_fused_kernel(
    const float* __restrict__ state,   // [64][128][16]
    const float* __restrict__ k1,      // [5][1][128]
    const float* __restrict__ b1,      // [128]
    const float* __restrict__ k2,      // [5][1][1024]
    const float* __restrict__ b2,      // [1024]
    const float* __restrict__ k3,      // [5][1][8192]
    const float* __restrict__ b3,      // [8192]
    const float* __restrict__ W,       // [950272][2]
    float* __restrict__ partials)      // [64][8][4][2]
{
    const int chunk = blockIdx.x;      // 0..7
    const int bg    = blockIdx.y;      // 0..15
    const int slice = blockIdx.z;      // 0..3
    const int t0    = slice * SLICE;
    const int tid   = threadIdx.x;     // 0..255
    const int c3loc = tid >> 1;        // 0..127
    const int fh    = tid & 1;         // 0..1
    const int c3    = chunk * 128 + c3loc;

    __shared__ float s_state[NBATCH][STR][2];   // 1.3 KB
    __shared__ v4f   s_y1[Y1R][16];             // lanes = batches, 9.25 KB
    __shared__ v4f   tile[TROWS][128];          // lanes = batches, 66 KB

    // ---- EARLY cold loads: no LDS dependency; issued before staging so
    // their miss latency overlaps conv1/conv2 compute ----
    const v4f* __restrict__ wb =
        (const v4f*)W + (size_t)t0 * 4096 + (size_t)c3 * 4 + fh * 2;
    v4f qa0 = wb[0],    qa1 = wb[1];       // W[t]   (even ring slot)
    v4f qb0 = wb[4096], qb1 = wb[4097];    // W[t+1] (odd ring slot)

    float kw[KW][NFH], bv[NFH];
#pragma unroll
    for (int k = 0; k < KW; ++k)
#pragma unroll
        for (int f = 0; f < NFH; ++f)
            kw[k][f] = k3[k * CH3 + c3 * NF + fh * NFH + f];
#pragma unroll
    for (int f = 0; f < NFH; ++f)
        bv[f] = b3[c3 * NF + fh * NFH + f];

    // ---- stage state: wave bb = tid>>6 owns batch bg*4+bb ----
    {
        int bb = tid >> 6, lt = tid & 63;
        const float* sp = state + (size_t)(bg * NBATCH + bb) * L0 * C0
                        + (size_t)t0 * C0 + chunk * 2;
        for (int i = lt; i < STR * 2; i += 64) {
            int r = i >> 1, c = i & 1;
            s_state[bb][r][c] = sp[r * C0 + c];
        }
    }
    __syncthreads();

    // ---- conv1: wave bb writes component bb of s_y1 ----
    {
        int bb = tid >> 6, lt = tid & 63;
        for (int i = lt; i < Y1R * 16; i += 64) {
            int r = i >> 4, jloc = i & 15;
            int j = chunk * 16 + jloc;
            int cloc = jloc >> 3;
            float acc = b1[j];
#pragma unroll
            for (int k = 0; k < KW; ++k)
                acc = fmaf(s_state[bb][r + k][cloc], k1[k * CH1 + j], acc);
            ((float*)&s_y1[r][jloc])[bb] = fmaxf(acc, 0.f);
        }
    }
    __syncthreads();

    // ---- conv2: col c = tid&127, row-half h = tid>>7, 4 batches packed ----
    {
        int c = tid & 127, h = tid >> 7;
        int m = chunk * 128 + c;
        int jloc = c >> 3;
        float kk[KW], b2v = b2[m];
#pragma unroll
        for (int k = 0; k < KW; ++k) kk[k] = k2[k * CH2 + m];
        int r0i = h ? 17 : 0, r1i = h ? TROWS : 17;
        v4f u0 = s_y1[r0i + 0][jloc];
        v4f u1 = s_y1[r0i + 1][jloc];
        v4f u2 = s_y1[r0i + 2][jloc];
        v4f u3 = s_y1[r0i + 3][jloc];
        for (int r = r0i; r < r1i; ++r) {
            v4f u4 = s_y1[r + 4][jloc];
            v4f acc = splat(b2v);
            acc = vfma(u0, kk[0], acc);
            acc = vfma(u1, kk[1], acc);
            acc = vfma(u2, kk[2], acc);
            acc = vfma(u3, kk[3], acc);
            acc = vfma(u4, kk[4], acc);
            tile[r][c] = vrelu(acc);
            u0 = u1; u1 = u2; u2 = u3; u3 = u4;
        }
    }

    __syncthreads();   // tile ready

    // ---- main loop: unroll-2, ring-2 W slots, double-row ds prefetch ----
    v4f accx = splat(0.f), accy = splat(0.f);

    v4f r0 = tile[0][c3loc], r1 = tile[1][c3loc], r2 = tile[2][c3loc],
        r3 = tile[3][c3loc], r4 = tile[4][c3loc], rn = tile[5][c3loc];

#define SUBITER(A0, A1, A2, A3, A4, Q0, Q1)                                   \
    {                                                                          \
        v4f v0 = splat(bv[0]), v1 = splat(bv[1]);                              \
        v4f v2 = splat(bv[2]), v3 = splat(bv[3]);                              \
        v0 = vfma(A0, kw[0][0], v0); v1 = vfma(A0, kw[0][1], v1);              \
        v2 = vfma(A0, kw[0][2], v2); v3 = vfma(A0, kw[0][3], v3);              \
        v0 = vfma(A1, kw[1][0], v0); v1 = vfma(A1, kw[1][1], v1);              \
        v2 = vfma(A1, kw[1][2], v2); v3 = vfma(A1, kw[1][3], v3);              \
        v0 = vfma(A2, kw[2][0], v0); v1 = vfma(A2, kw[2][1], v1);              \
        v2 = vfma(A2, kw[2][2], v2); v3 = vfma(A2, kw[2][3], v3);              \
        v0 = vfma(A3, kw[3][0], v0); v1 = vfma(A3, kw[3][1], v1);              \
        v2 = vfma(A3, kw[3][2], v2); v3 = vfma(A3, kw[3][3], v3);              \
        v0 = vfma(A4, kw[4][0], v0); v1 = vfma(A4, kw[4][1], v1);              \
        v2 = vfma(A4, kw[4][2], v2); v3 = vfma(A4, kw[4][3], v3);              \
        v0 = vrelu(v0); v1 = vrelu(v1); v2 = vrelu(v2); v3 = vrelu(v3);        \
        accx = vfma(v0, Q0.x, accx); accy = vfma(v0, Q0.y, accy);              \
        accx = vfma(v1, Q0.z, accx); accy = vfma(v1, Q0.w, accy);              \
        accx = vfma(v2, Q1.x, accx); accy = vfma(v2, Q1.y, accy);              \
        accx = vfma(v3, Q1.z, accx); accy = vfma(v3, Q1.w, accy);              \
    }

    for (int t = 0; t < SLICE - 1; t += 2) {   // t = 0,2,...,26
        // ds prefetch for the NEXT double-iter
        v4f na = tile[t + 6][c3loc];
        int tb = (t + 7 < TROWS) ? (t + 7) : (TROWS - 1);
        v4f nb = tile[tb][c3loc];

        SUBITER(r0, r1, r2, r3, r4, qa0, qa1);
        qa0 = wb[(size_t)(t + 2) * 4096];
        qa1 = wb[(size_t)(t + 2) * 4096 + 1];

        SUBITER(r1, r2, r3, r4, rn, qb0, qb1);
        int tp = (t + 3 < SLICE) ? (t + 3) : (SLICE - 1);
        qb0 = wb[(size_t)tp * 4096];
        qb1 = wb[(size_t)tp * 4096 + 1];

        r0 = r2; r1 = r3; r2 = r4; r3 = rn; r4 = na; rn = nb;
    }
    SUBITER(r0, r1, r2, r3, r4, qa0, qa1);   // tail t = 28
#undef SUBITER

    // ---- reductions: 4 batches x 2 outputs ----
    float ax[NBATCH] = {accx.x, accx.y, accx.z, accx.w};
    float ay[NBATCH] = {accy.x, accy.y, accy.z, accy.w};
#pragma unroll
    for (int bb = 0; bb < NBATCH; ++bb)
#pragma unroll
        for (int d = 32; d >= 1; d >>= 1) {
            ax[bb] += __shfl_down(ax[bb], d, 64);
            ay[bb] += __shfl_down(ay[bb], d, 64);
        }
    __shared__ float red[4][NBATCH][2];
    int wave = tid >> 6, lane = tid & 63;
    if (lane == 0) {
#pragma unroll
        for (int bb = 0; bb < NBATCH; ++bb) {
            red[wave][bb][0] = ax[bb];
            red[wave][bb][1] = ay[bb];
        }
    }
    __syncthreads();
    if (tid < NBATCH * 2) {
        int bb = tid >> 1, a = tid & 1;
        float s = (red[0][bb][a] + red[1][bb][a]) + (red[2][bb][a] + red[3][bb][a]);
        int b = bg * NBATCH + bb;
        partials[(((size_t)b * NCHUNK + chunk) * NS + slice) * 2 + a] = s;
    }
}

// ---------------------------------------------------------------------------
__global__ __launch_bounds__(128) void finish_kernel(
    const float* __restrict__ partials,  // [64][8][4][2]
    const float* __restrict__ bd,        // [2]
    float* __restrict__ out)             // [64][2]
{
    int i = threadIdx.x;
    int b = i >> 1, a = i & 1;
    float s = bd[a];
#pragma unroll
    for (int p = 0; p < NCHUNK * NS; ++p)
        s += partials[((size_t)b * NCHUNK * NS + p) * 2 + a];
    out[b * 2 + a] = tanhf(s);
}

extern "C" void kernel_launch(void* const* d_in, const int* in_sizes, int n_in,
                              void* d_out, int out_size, void* d_ws, size_t ws_size,
                              hipStream_t stream) {
    const float* state = (const float*)d_in[0];
    const float* k1    = (const float*)d_in[1];
    const float* b1    = (const float*)d_in[2];
    const float* k2    = (const float*)d_in[3];
    const float* b2    = (const float*)d_in[4];
    const float* k3    = (const float*)d_in[5];
    const float* b3    = (const float*)d_in[6];
    const float* W     = (const float*)d_in[7];
    const float* bd    = (const float*)d_in[8];
    float* out = (float*)d_out;

    float* partials = (float*)d_ws;   // 64*8*4*2 fp32 = 16 KB

    dim3 grid(NCHUNK, NBG, NS);
    actor_fused_kernel<<<grid, 256, 0, stream>>>(
        state, k1, b1, k2, b2, k3, b3, W, partials);

    finish_kernel<<<1, 128, 0, stream>>>(partials, bd, out);
}

// Round 13
// 90.787 us; speedup vs baseline: 1.3818x; 1.0184x over previous
//
#include <hip/hip_runtime.h>
#include <math.h>

// Problem constants
#define NB    64
#define L0    128
#define C0    16
#define KW    5
#define NF    8
#define CH1   128
#define CH2   1024
#define CH3   8192
#define NCHUNK 8
#define NS     4
#define SLICE  29
#define TROWS  (SLICE + 4)    // 33
#define Y1R    (SLICE + 8)    // 37
#define STR    (SLICE + 12)   // 41
#define NFH    4
#define NBATCH 4              // batches per block (2 blocks/CU)
#define NBG    (NB / NBATCH)  // 16

typedef float v4f __attribute__((ext_vector_type(4)));

__device__ __forceinline__ v4f splat(float s) { return (v4f){s, s, s, s}; }
// a*s + c, elementwise -> v_pk_fma_f32 pairs on gfx950
__device__ __forceinline__ v4f vfma(v4f a, float s, v4f c) {
    return __builtin_elementwise_fma(a, splat(s), c);
}
__device__ __forceinline__ v4f vrelu(v4f a) {
    return __builtin_elementwise_max(a, splat(0.f));
}

// ---------------------------------------------------------------------------
// R13 = exact revert to R9, the measured optimum (89.3 us total; fused
// ~14.7 us warm per the R8 4x-launch calibration). Unroll-2 main loop with
// ring-2 W prefetch (refill-after-consume, consumed one full double-iter
// later), double-row ds prefetch, NBATCH=4 packed-fp32, 2 blocks/CU.
// Perturbations probed and rejected: full unroll (+2.6 us, R10), cold-load
// hoist (+3.2 us, R12), fence-fused finish (+36 us, R11), NBATCH=2 @ 4
// blocks/CU (neutral, R6), register pinning (+2 us, R7).
// blockIdx.x = chunk pins each 950 KB W-slice to one XCD's L2 (linear%8).
// ---------------------------------------------------------------------------
__global__ __launch_bounds__(256, 2) void actor_fused_kernel(
    const float* __restrict__ state,   // [64][128][16]
    const float* __restrict__ k1,      // [5][1][128]
    const float* __restrict__ b1,      // [128]
    const float* __restrict__ k2,      // [5][1][1024]
    const float* __restrict__ b2,      // [1024]
    const float* __restrict__ k3,      // [5][1][8192]
    const float* __restrict__ b3,      // [8192]
    const float* __restrict__ W,       // [950272][2]
    float* __restrict__ partials)      // [64][8][4][2]
{
    const int chunk = blockIdx.x;      // 0..7
    const int bg    = blockIdx.y;      // 0..15
    const int slice = blockIdx.z;      // 0..3
    const int t0    = slice * SLICE;
    const int tid   = threadIdx.x;     // 0..255
    const int c3loc = tid >> 1;        // 0..127
    const int fh    = tid & 1;         // 0..1
    const int c3    = chunk * 128 + c3loc;

    __shared__ float s_state[NBATCH][STR][2];   // 1.3 KB
    __shared__ v4f   s_y1[Y1R][16];             // lanes = batches, 9.25 KB
    __shared__ v4f   tile[TROWS][128];          // lanes = batches, 66 KB

    // ---- stage state: wave bb = tid>>6 owns batch bg*4+bb ----
    {
        int bb = tid >> 6, lt = tid & 63;
        const float* sp = state + (size_t)(bg * NBATCH + bb) * L0 * C0
                        + (size_t)t0 * C0 + chunk * 2;
        for (int i = lt; i < STR * 2; i += 64) {
            int r = i >> 1, c = i & 1;
            s_state[bb][r][c] = sp[r * C0 + c];
        }
    }
    __syncthreads();

    // ---- conv1: wave bb writes component bb of s_y1 ----
    {
        int bb = tid >> 6, lt = tid & 63;
        for (int i = lt; i < Y1R * 16; i += 64) {
            int r = i >> 4, jloc = i & 15;
            int j = chunk * 16 + jloc;
            int cloc = jloc >> 3;
            float acc = b1[j];
#pragma unroll
            for (int k = 0; k < KW; ++k)
                acc = fmaf(s_state[bb][r + k][cloc], k1[k * CH1 + j], acc);
            ((float*)&s_y1[r][jloc])[bb] = fmaxf(acc, 0.f);
        }
    }
    __syncthreads();

    // ---- conv2: col c = tid&127, row-half h = tid>>7, all 4 batches packed ----
    {
        int c = tid & 127, h = tid >> 7;
        int m = chunk * 128 + c;
        int jloc = c >> 3;
        float kk[KW], b2v = b2[m];
#pragma unroll
        for (int k = 0; k < KW; ++k) kk[k] = k2[k * CH2 + m];
        int r0i = h ? 17 : 0, r1i = h ? TROWS : 17;
        v4f u0 = s_y1[r0i + 0][jloc];
        v4f u1 = s_y1[r0i + 1][jloc];
        v4f u2 = s_y1[r0i + 2][jloc];
        v4f u3 = s_y1[r0i + 3][jloc];
        for (int r = r0i; r < r1i; ++r) {
            v4f u4 = s_y1[r + 4][jloc];
            v4f acc = splat(b2v);
            acc = vfma(u0, kk[0], acc);
            acc = vfma(u1, kk[1], acc);
            acc = vfma(u2, kk[2], acc);
            acc = vfma(u3, kk[3], acc);
            acc = vfma(u4, kk[4], acc);
            tile[r][c] = vrelu(acc);
            u0 = u1; u1 = u2; u2 = u3; u3 = u4;
        }
    }

    // ---- conv3 weights + bias (scalar, register-resident) ----
    float kw[KW][NFH], bv[NFH];
#pragma unroll
    for (int k = 0; k < KW; ++k)
#pragma unroll
        for (int f = 0; f < NFH; ++f)
            kw[k][f] = k3[k * CH3 + c3 * NF + fh * NFH + f];
#pragma unroll
    for (int f = 0; f < NFH; ++f)
        bv[f] = b3[c3 * NF + fh * NFH + f];

    __syncthreads();   // tile ready

    // ---- main loop: unroll-2, ring-2 W slots, double-row ds prefetch ----
    v4f accx = splat(0.f), accy = splat(0.f);

    const v4f* __restrict__ wb =
        (const v4f*)W + (size_t)t0 * 4096 + (size_t)c3 * 4 + fh * 2;
    v4f qa0 = wb[0],    qa1 = wb[1];       // W[t]   (even slot)
    v4f qb0 = wb[4096], qb1 = wb[4097];    // W[t+1] (odd slot)

    v4f r0 = tile[0][c3loc], r1 = tile[1][c3loc], r2 = tile[2][c3loc],
        r3 = tile[3][c3loc], r4 = tile[4][c3loc], rn = tile[5][c3loc];

#define SUBITER(A0, A1, A2, A3, A4, Q0, Q1)                                   \
    {                                                                          \
        v4f v0 = splat(bv[0]), v1 = splat(bv[1]);                              \
        v4f v2 = splat(bv[2]), v3 = splat(bv[3]);                              \
        v0 = vfma(A0, kw[0][0], v0); v1 = vfma(A0, kw[0][1], v1);              \
        v2 = vfma(A0, kw[0][2], v2); v3 = vfma(A0, kw[0][3], v3);              \
        v0 = vfma(A1, kw[1][0], v0); v1 = vfma(A1, kw[1][1], v1);              \
        v2 = vfma(A1, kw[1][2], v2); v3 = vfma(A1, kw[1][3], v3);              \
        v0 = vfma(A2, kw[2][0], v0); v1 = vfma(A2, kw[2][1], v1);              \
        v2 = vfma(A2, kw[2][2], v2); v3 = vfma(A2, kw[2][3], v3);              \
        v0 = vfma(A3, kw[3][0], v0); v1 = vfma(A3, kw[3][1], v1);              \
        v2 = vfma(A3, kw[3][2], v2); v3 = vfma(A3, kw[3][3], v3);              \
        v0 = vfma(A4, kw[4][0], v0); v1 = vfma(A4, kw[4][1], v1);              \
        v2 = vfma(A4, kw[4][2], v2); v3 = vfma(A4, kw[4][3], v3);              \
        v0 = vrelu(v0); v1 = vrelu(v1); v2 = vrelu(v2); v3 = vrelu(v3);        \
        accx = vfma(v0, Q0.x, accx); accy = vfma(v0, Q0.y, accy);              \
        accx = vfma(v1, Q0.z, accx); accy = vfma(v1, Q0.w, accy);              \
        accx = vfma(v2, Q1.x, accx); accy = vfma(v2, Q1.y, accy);              \
        accx = vfma(v3, Q1.z, accx); accy = vfma(v3, Q1.w, accy);              \
    }

    for (int t = 0; t < SLICE - 1; t += 2) {   // t = 0,2,...,26
        // ds prefetch for the NEXT double-iter (consumed ~130 inst later)
        v4f na = tile[t + 6][c3loc];
        int tb = (t + 7 < TROWS) ? (t + 7) : (TROWS - 1);
        v4f nb = tile[tb][c3loc];

        // even sub-iter: rows t..t+4, W[t]; refill slot A with W[t+2]
        SUBITER(r0, r1, r2, r3, r4, qa0, qa1);
        qa0 = wb[(size_t)(t + 2) * 4096];
        qa1 = wb[(size_t)(t + 2) * 4096 + 1];

        // odd sub-iter: rows t+1..t+5, W[t+1]; refill slot B with W[t+3]
        SUBITER(r1, r2, r3, r4, rn, qb0, qb1);
        int tp = (t + 3 < SLICE) ? (t + 3) : (SLICE - 1);
        qb0 = wb[(size_t)tp * 4096];
        qb1 = wb[(size_t)tp * 4096 + 1];

        // shift window by 2
        r0 = r2; r1 = r3; r2 = r4; r3 = rn; r4 = na; rn = nb;
    }
    // tail sub-iter t = 28: rows 28..32, W[28] (slot A)
    SUBITER(r0, r1, r2, r3, r4, qa0, qa1);
#undef SUBITER

    // ---- reductions: 4 batches x 2 outputs ----
    float ax[NBATCH] = {accx.x, accx.y, accx.z, accx.w};
    float ay[NBATCH] = {accy.x, accy.y, accy.z, accy.w};
#pragma unroll
    for (int bb = 0; bb < NBATCH; ++bb)
#pragma unroll
        for (int d = 32; d >= 1; d >>= 1) {
            ax[bb] += __shfl_down(ax[bb], d, 64);
            ay[bb] += __shfl_down(ay[bb], d, 64);
        }
    __shared__ float red[4][NBATCH][2];
    int wave = tid >> 6, lane = tid & 63;
    if (lane == 0) {
#pragma unroll
        for (int bb = 0; bb < NBATCH; ++bb) {
            red[wave][bb][0] = ax[bb];
            red[wave][bb][1] = ay[bb];
        }
    }
    __syncthreads();
    if (tid < NBATCH * 2) {
        int bb = tid >> 1, a = tid & 1;
        float s = (red[0][bb][a] + red[1][bb][a]) + (red[2][bb][a] + red[3][bb][a]);
        int b = bg * NBATCH + bb;
        partials[(((size_t)b * NCHUNK + chunk) * NS + slice) * 2 + a] = s;
    }
}

// ---------------------------------------------------------------------------
__global__ __launch_bounds__(128) void finish_kernel(
    const float* __restrict__ partials,  // [64][8][4][2]
    const float* __restrict__ bd,        // [2]
    float* __restrict__ out)             // [64][2]
{
    int i = threadIdx.x;
    int b = i >> 1, a = i & 1;
    float s = bd[a];
#pragma unroll
    for (int p = 0; p < NCHUNK * NS; ++p)
        s += partials[((size_t)b * NCHUNK * NS + p) * 2 + a];
    out[b * 2 + a] = tanhf(s);
}

extern "C" void kernel_launch(void* const* d_in, const int* in_sizes, int n_in,
                              void* d_out, int out_size, void* d_ws, size_t ws_size,
                              hipStream_t stream) {
    const float* state = (const float*)d_in[0];
    const float* k1    = (const float*)d_in[1];
    const float* b1    = (const float*)d_in[2];
    const float* k2    = (const float*)d_in[3];
    const float* b2    = (const float*)d_in[4];
    const float* k3    = (const float*)d_in[5];
    const float* b3    = (const float*)d_in[6];
    const float* W     = (const float*)d_in[7];
    const float* bd    = (const float*)d_in[8];
    float* out = (float*)d_out;

    float* partials = (float*)d_ws;   // 64*8*4*2 fp32 = 16 KB

    dim3 grid(NCHUNK, NBG, NS);
    actor_fused_kernel<<<grid, 256, 0, stream>>>(
        state, k1, b1, k2, b2, k3, b3, W, partials);

    finish_kernel<<<1, 128, 0, stream>>>(partials, bd, out);
}